// Round 5
// baseline (358.605 us; speedup 1.0000x reference)
//
#include <hip/hip_runtime.h>

// Sequential 5x5 cellular scatter, 48x48, 8192 batches, fp32.
// R5: producer-consumer 2-wave blocks. R4 post-mortem showed we are DS-pipe
// issue-bound (~87us floor of b32 LDS traffic, 60% DS-busy) at 1 wave/SIMD.
// Changes:
//  - Block = 128 threads (2 waves), 4 batches. wave0 = forward recurrence
//    (wavefronts t), wave1 = interior finalize as a trailing wavefront
//    (tau = t-12; finalize(tau) needs V only up to wavefront tau+8, and those
//    values are final). Sync = raw s_barrier + lgkmcnt(0) publish every
//    4 steps (NOT __syncthreads: would vmcnt(0)-drain the weight prefetch).
//    Phase p: wave0 writes wavefronts 4p..4p+3; wave1 reads <= 4p-1 -> disjoint.
//  - 8 waves/CU (2/SIMD): latency gaps now coverable; finalize DS overlaps
//    forward latency instead of being a serial second phase.
//  - Finalize weights re-tabulated wavefront-major (FWseq[tau][slot][16]) so
//    wave1 prefetches linearly, distance 4, like wave0's WFseq.
//  - Border tail: split across all 128 threads after the main loops (reads V
//    only -> no extra barrier needed; out writes disjoint from wave1's).

#define SZ 48
#define DP 2
#define NC (SZ * SZ)        // 2304
#define NBATCH 4
#define GS 2308             // LDS grid stride (floats)
#define PADH 104            // zeroed halo floats each side
#define NT 128              // 2 waves
#define NPHASE 47           // phases of 4 steps; t=0..187 fwd, tau=-12..175 fin

#define TSTEPS 180          // WFseq entries (fwd), clamped loads
#define FTSTEPS 184         // FWseq entries (fin), clamped loads
#define NBOR 368
#define NBOR_ALLOC 512

#define WF_FLOATS (TSTEPS * 16 * 12)        // 34560
#define FW_FLOATS (FTSTEPS * 16 * 16)       // 47104
#define FB_FLOATS (NBOR_ALLOC * 24)         // 12288
// ws total: 93952 floats = 375,808 B

__device__ __forceinline__ bool is_in(int v) {
    return (unsigned)(v - DP) <= (unsigned)(SZ - 2 * DP - 1);   // [2,45]
}

// ---------------- table construction ----------------
__global__ void prep_kernel(const float* __restrict__ w, float* __restrict__ ws)
{
    int id = blockIdx.x * 256 + threadIdx.x;
    float* WFseq = ws;
    float* FWseq = ws + WF_FLOATS;
    float* FBc   = FWseq + FW_FLOATS;

    if (id < TSTEPS * 16) {
        // forward gather weights per (t, slot)
        int t = id >> 4, s = id & 15;
        float vals[12];
        #pragma unroll
        for (int k = 0; k < 12; ++k) vals[k] = 0.f;
        if (t < 173) {
            int xlo = (t > 43) ? (t - 41) / 3 : 0;
            int xhi = t / 3; if (xhi > 43) xhi = 43;
            int x2 = xlo + s;
            if (x2 <= xhi) {
                int y2 = t - 3 * x2;
                int y = y2 + DP, x = x2 + DP, c = y * SZ + x;
                const int edy[12] = {-2,-1, 0, 1, 2, -2,-1, 0, 1, 2, -2,-1};
                const int edx[12] = {-2,-2,-2,-2,-2, -1,-1,-1,-1,-1,  0, 0};
                #pragma unroll
                for (int k = 0; k < 12; ++k) {
                    int dy = edy[k], dx = edx[k];
                    if (is_in(y + dy) && is_in(x + dx)) {
                        int nc = c + dy * SZ + dx;
                        vals[k] = w[nc * 25 + (DP - dy) * 5 + (DP - dx)];
                    }
                }
            }
        }
        float* o = WFseq + id * 12;
        #pragma unroll
        for (int k = 0; k < 12; ++k) o[k] = vals[k];
        return;
    }
    int id2 = id - TSTEPS * 16;
    if (id2 < FTSTEPS * 16) {
        // finalize weights per (tau, slot): [0]=center, [1..12]=later nbrs
        int t = id2 >> 4, s = id2 & 15;
        float vals[16];
        #pragma unroll
        for (int k = 0; k < 16; ++k) vals[k] = 0.f;
        if (t < 173) {
            int xlo = (t > 43) ? (t - 41) / 3 : 0;
            int xhi = t / 3; if (xhi > 43) xhi = 43;
            int x2 = xlo + s;
            if (x2 <= xhi) {
                int y2 = t - 3 * x2;
                int y = y2 + DP, x = x2 + DP, c = y * SZ + x;
                vals[0] = w[c * 25 + 12];
                const int ldy[12] = { 1, 2, -2,-1, 0, 1, 2, -2,-1, 0, 1, 2};
                const int ldx[12] = { 0, 0,  1, 1, 1, 1, 1,  2, 2, 2, 2, 2};
                #pragma unroll
                for (int k = 0; k < 12; ++k) {
                    int dy = ldy[k], dx = ldx[k];
                    if (is_in(y + dy) && is_in(x + dx)) {
                        int nc = c + dy * SZ + dx;
                        vals[1 + k] = w[nc * 25 + (DP - dy) * 5 + (DP - dx)];
                    }
                }
            }
        }
        float* o = FWseq + id2 * 16;
        #pragma unroll
        for (int k = 0; k < 16; ++k) o[k] = vals[k];
        return;
    }
    int id3 = id2 - FTSTEPS * 16;
    if (id3 < NBOR_ALLOC) {
        float vals[24];
        #pragma unroll
        for (int k = 0; k < 24; ++k) vals[k] = 0.f;
        if (id3 < NBOR) {
            int y, x;
            if (id3 < 96)       { y = id3 / 48;             x = id3 - (id3 / 48) * 48; }
            else if (id3 < 192) { int j = id3 - 96;  y = 46 + j / 48; x = j - (j / 48) * 48; }
            else                { int j = id3 - 192; y = 2 + (j >> 2); int q = j & 3; x = q + (q >= 2 ? 44 : 0); }
            int c = y * SZ + x;
            int k = 0;
            #pragma unroll
            for (int dy = -2; dy <= 2; ++dy) {
                #pragma unroll
                for (int dx = -2; dx <= 2; ++dx) {
                    if (dy == 0 && dx == 0) continue;
                    if (is_in(y + dy) && is_in(x + dx)) {
                        int nc = c + dy * SZ + dx;
                        vals[k] = w[nc * 25 + (DP - dy) * 5 + (DP - dx)];
                    }
                    ++k;
                }
            }
        }
        float* o = FBc + id3 * 24;
        #pragma unroll
        for (int k = 0; k < 24; ++k) o[k] = vals[k];
    }
}

// ---------------- device helpers ----------------
__device__ __forceinline__ void do_step(int tt, int s, float* gb,
                                        float4 w0, float4 w1, float4 w2)
{
    int xlo = (tt > 43) ? (tt - 41) / 3 : 0;
    int xhi = tt / 3; if (xhi > 43) xhi = 43;
    int x2 = xlo + s;
    if (x2 <= xhi) {
        int cell = (tt - 3 * x2 + DP) * SZ + x2 + DP;
        const float* p = gb + cell - 98;
        float a0 = w0.x * p[0]   + w0.y * p[48]  + w0.z * p[96] + w0.w * p[144];
        float a1 = w1.x * p[192] + w1.y * p[1]   + w1.z * p[49] + w1.w * p[97];
        float a2 = w2.x * p[145] + w2.y * p[193] + w2.z * p[2]  + w2.w * p[50];
        gb[cell] = p[98] + a0 + a1 + a2;
    }
}

__device__ __forceinline__ void loadw3(const float* wfbase, int tt,
                                       float4& w0, float4& w1, float4& w2)
{
    int ci = tt < TSTEPS - 1 ? tt : TSTEPS - 1;
    const float4* q = (const float4*)(wfbase + ci * 192);
    w0 = q[0]; w1 = q[1]; w2 = q[2];
}

__device__ __forceinline__ void fin_step(int tt, int s, const float* gb, float* outp,
                                         float4 f0, float4 f1, float4 f2, float4 f3)
{
    if ((unsigned)tt > 172u) return;
    int xlo = (tt > 43) ? (tt - 41) / 3 : 0;
    int xhi = tt / 3; if (xhi > 43) xhi = 43;
    int x2 = xlo + s;
    if (x2 <= xhi) {
        int cell = (tt - 3 * x2 + DP) * SZ + x2 + DP;
        const float* p = gb + cell - 95;
        float o = f0.x * p[95]  + f0.y * p[143] + f0.z * p[191] + f0.w * p[0]
                + f1.x * p[48]  + f1.y * p[96]  + f1.z * p[144] + f1.w * p[192]
                + f2.x * p[1]   + f2.y * p[49]  + f2.z * p[97]  + f2.w * p[145]
                + f3.x * p[193];
        outp[cell] = o;
    }
}

__device__ __forceinline__ void loadw4(const float* fwbase, int tt,
                                       float4& f0, float4& f1, float4& f2, float4& f3)
{
    int ci = tt < 0 ? 0 : (tt < FTSTEPS - 1 ? tt : FTSTEPS - 1);
    const float4* q = (const float4*)(fwbase + ci * 256);
    f0 = q[0]; f1 = q[1]; f2 = q[2]; f3 = q[3];
}

__device__ __forceinline__ void publish_barrier() {
    asm volatile("s_waitcnt lgkmcnt(0)" ::: "memory");
    __builtin_amdgcn_s_barrier();
    asm volatile("" ::: "memory");
}
__device__ __forceinline__ void consume_barrier() {
    asm volatile("" ::: "memory");
    __builtin_amdgcn_s_barrier();
    asm volatile("" ::: "memory");
}

// ---------------- main kernel ----------------
__global__ __launch_bounds__(NT)
void ca_kernel(const float* __restrict__ in, const float* __restrict__ ws,
               float* __restrict__ out)
{
    __shared__ float gmem[PADH + NBATCH * GS + PADH];
    float* g = gmem + PADH;
    const int tid = threadIdx.x;
    const int b0  = blockIdx.x * NBATCH;

    // zero halos, load 4 grids (128 threads cooperatively)
    for (int i = tid; i < PADH; i += NT) { gmem[i] = 0.f; gmem[PADH + NBATCH * GS + i] = 0.f; }
    #pragma unroll
    for (int b = 0; b < NBATCH; ++b) {
        const float4* src = (const float4*)(in + (size_t)(b0 + b) * NC);
        float4* dst = (float4*)(g + b * GS);
        for (int i = tid; i < NC / 4; i += NT) dst[i] = src[i];
    }
    __syncthreads();

    const int wid  = tid >> 6;
    const int lane = tid & 63;
    const int bl   = lane & (NBATCH - 1);
    const int s    = lane >> 2;
    float* gb = g + bl * GS;

    if (wid == 0) {
        // -------- producer: forward wavefront recurrence --------
        const float* wfbase = ws + s * 12;           // step stride 192 floats
        float4 A0, A1, A2, B0, B1, B2, C0, C1, C2, D0, D1, D2;
        loadw3(wfbase, 0, A0, A1, A2);
        loadw3(wfbase, 1, B0, B1, B2);
        loadw3(wfbase, 2, C0, C1, C2);
        loadw3(wfbase, 3, D0, D1, D2);
        for (int p = 0; p < NPHASE; ++p) {
            int t = p * 4;
            do_step(t + 0, s, gb, A0, A1, A2);  loadw3(wfbase, t + 4, A0, A1, A2);
            do_step(t + 1, s, gb, B0, B1, B2);  loadw3(wfbase, t + 5, B0, B1, B2);
            do_step(t + 2, s, gb, C0, C1, C2);  loadw3(wfbase, t + 6, C0, C1, C2);
            do_step(t + 3, s, gb, D0, D1, D2);  loadw3(wfbase, t + 7, D0, D1, D2);
            publish_barrier();
        }
    } else {
        // -------- consumer: trailing interior finalize (lag 12) --------
        const float* fwbase = ws + WF_FLOATS + s * 16;   // step stride 256 floats
        float* outp = out + (size_t)(b0 + bl) * NC;
        float4 A0, A1, A2, A3, B0, B1, B2, B3, C0, C1, C2, C3, D0, D1, D2, D3;
        loadw4(fwbase, -12, A0, A1, A2, A3);
        loadw4(fwbase, -11, B0, B1, B2, B3);
        loadw4(fwbase, -10, C0, C1, C2, C3);
        loadw4(fwbase,  -9, D0, D1, D2, D3);
        for (int p = 0; p < NPHASE; ++p) {
            int tau = p * 4 - 12;
            fin_step(tau + 0, s, gb, outp, A0, A1, A2, A3);  loadw4(fwbase, tau + 4, A0, A1, A2, A3);
            fin_step(tau + 1, s, gb, outp, B0, B1, B2, B3);  loadw4(fwbase, tau + 5, B0, B1, B2, B3);
            fin_step(tau + 2, s, gb, outp, C0, C1, C2, C3);  loadw4(fwbase, tau + 6, C0, C1, C2, C3);
            fin_step(tau + 3, s, gb, outp, D0, D1, D2, D3);  loadw4(fwbase, tau + 7, D0, D1, D2, D3);
            consume_barrier();
        }
    }

    // -------- border finalize: all 128 threads, reads V only --------
    {
        const float* FBc = ws + WF_FLOATS + FW_FLOATS;
        const float4* fp = (const float4*)(FBc + tid * 24);
        float4 f0 = fp[0], f1 = fp[1], f2 = fp[2], f3 = fp[3], f4 = fp[4], f5 = fp[5];
        for (int it = 0; it < 3; ++it) {
            int idx = it * NT + tid;
            const float4* np = (const float4*)(FBc + (idx + NT) * 24);
            float4 n0 = np[0], n1 = np[1], n2 = np[2], n3 = np[3], n4 = np[4], n5 = np[5];
            if (idx < NBOR) {
                int y, x;
                if (idx < 96)       { y = idx / 48;            x = idx - (idx / 48) * 48; }
                else if (idx < 192) { int j = idx - 96;  y = 46 + j / 48; x = j - (j / 48) * 48; }
                else                { int j = idx - 192; y = 2 + (j >> 2); int q = j & 3; x = q + (q >= 2 ? 44 : 0); }
                int c = y * SZ + x;
                #pragma unroll
                for (int b = 0; b < NBATCH; ++b) {
                    const float* p = g + b * GS + c - 98;   // halo makes reads safe
                    float o = p[98]
                        + f0.x * p[0]   + f0.y * p[1]   + f0.z * p[2]   + f0.w * p[3]
                        + f1.x * p[4]   + f1.y * p[48]  + f1.z * p[49]  + f1.w * p[50]
                        + f2.x * p[51]  + f2.y * p[52]  + f2.z * p[96]  + f2.w * p[97]
                        + f3.x * p[99]  + f3.y * p[100] + f3.z * p[144] + f3.w * p[145]
                        + f4.x * p[146] + f4.y * p[147] + f4.z * p[148] + f4.w * p[192]
                        + f5.x * p[193] + f5.y * p[194] + f5.z * p[195] + f5.w * p[196];
                    out[(size_t)(b0 + b) * NC + c] = o;
                }
            }
            f0 = n0; f1 = n1; f2 = n2; f3 = n3; f4 = n4; f5 = n5;
        }
    }
}

extern "C" void kernel_launch(void* const* d_in, const int* in_sizes, int n_in,
                              void* d_out, int out_size, void* d_ws, size_t ws_size,
                              hipStream_t stream)
{
    const float* in = (const float*)d_in[0];
    const float* w  = (const float*)d_in[1];
    float* out = (float*)d_out;
    float* ws  = (float*)d_ws;   // needs 375,808 B

    const int batch   = in_sizes[0] / NC;    // 8192
    const int nblocks = batch / NBATCH;      // 2048

    prep_kernel<<<25, 256, 0, stream>>>(w, ws);   // 6400 threads cover all tables
    ca_kernel<<<nblocks, NT, 0, stream>>>(in, ws, out);
}

// Round 6
// 297.162 us; speedup vs baseline: 1.2068x; 1.2068x over previous
//
#include <hip/hip_runtime.h>
#include <hip/hip_fp16.h>

// Sequential 5x5 cellular scatter, 48x48, 8192 batches, fp32.
// R6 = R5 producer-consumer structure, but finalize writes IN PLACE into the
// LDS grid (interior finalize reads only strictly-later-wavefront cells, so
// overwriting V(cell) with out(cell) at trailing lag 12 is race-free), ring V
// values (width-2 interior ring, 336 cells) stashed as f16 in a side array
// for the border pass, and a single fully-coalesced float4 grid->out copy at
// the end. This removes R5's 717MB of scattered 4B global writes (~75MB now).
// LDS 39.6KB -> 4 blocks/CU -> 8 waves/CU, 2048 blocks = 2 rounds.

#define SZ 48
#define DP 2
#define NC (SZ * SZ)        // 2304
#define NBATCH 4
#define GS 2308             // LDS grid stride (floats)
#define NT 128              // 2 waves
#define NPHASE 47           // 4 steps/phase; fwd t=0..187, fin tau=-12..175

#define TSTEPS 180
#define FTSTEPS 184
#define NBOR 368
#define NRING 336

#define WF_FLOATS (TSTEPS * 16 * 12)        // 34560
#define FW_FLOATS (FTSTEPS * 16 * 16)       // 47104
#define FB_STRIDE 36                        // 24 w + 24 u16 idx (12 words)
#define FB_FLOATS (NBOR * FB_STRIDE)        // 13248
// ws total: 94912 floats = 379,648 B

__device__ __forceinline__ bool is_in(int v) {
    return (unsigned)(v - DP) <= (unsigned)(SZ - 2 * DP - 1);   // [2,45]
}

// ring id for interior coords (y2,x2 in 0..43); -1 if not in width-2 ring
__device__ __forceinline__ int ring_id(int y2, int x2) {
    if (y2 < 2)  return y2 * 44 + x2;                  // 0..87
    if (y2 > 41) return 88 + (y2 - 42) * 44 + x2;      // 88..175
    if (x2 < 2)  return 176 + x2 * 40 + (y2 - 2);      // 176..255
    if (x2 > 41) return 256 + (x2 - 42) * 40 + (y2 - 2); // 256..335
    return -1;
}

__device__ __forceinline__ void border_yx(int idx, int& y, int& x) {
    if (idx < 96)       { y = idx / 48;            x = idx - (idx / 48) * 48; }
    else if (idx < 192) { int j = idx - 96;  y = 46 + j / 48; x = j - (j / 48) * 48; }
    else                { int j = idx - 192; y = 2 + (j >> 2); int q = j & 3; x = q + (q >= 2 ? 44 : 0); }
}

// ---------------- table construction ----------------
__global__ void prep_kernel(const float* __restrict__ w, float* __restrict__ ws)
{
    int id = blockIdx.x * 256 + threadIdx.x;
    float* WFseq = ws;
    float* FWseq = ws + WF_FLOATS;
    float* FBn   = FWseq + FW_FLOATS;

    if (id < TSTEPS * 16) {
        // forward gather weights per (t, slot)
        int t = id >> 4, s = id & 15;
        float vals[12];
        #pragma unroll
        for (int k = 0; k < 12; ++k) vals[k] = 0.f;
        if (t < 173) {
            int xlo = (t > 43) ? (t - 41) / 3 : 0;
            int xhi = t / 3; if (xhi > 43) xhi = 43;
            int x2 = xlo + s;
            if (x2 <= xhi) {
                int y2 = t - 3 * x2;
                int y = y2 + DP, x = x2 + DP, c = y * SZ + x;
                const int edy[12] = {-2,-1, 0, 1, 2, -2,-1, 0, 1, 2, -2,-1};
                const int edx[12] = {-2,-2,-2,-2,-2, -1,-1,-1,-1,-1,  0, 0};
                #pragma unroll
                for (int k = 0; k < 12; ++k) {
                    int dy = edy[k], dx = edx[k];
                    if (is_in(y + dy) && is_in(x + dx)) {
                        int nc = c + dy * SZ + dx;
                        vals[k] = w[nc * 25 + (DP - dy) * 5 + (DP - dx)];
                    }
                }
            }
        }
        float* o = WFseq + id * 12;
        #pragma unroll
        for (int k = 0; k < 12; ++k) o[k] = vals[k];
        return;
    }
    int id2 = id - TSTEPS * 16;
    if (id2 < FTSTEPS * 16) {
        // finalize weights per (tau, slot): [0]=center w, [1..12]=later nbrs,
        // [13]=ring_id+1 (0 if not ring), [14,15]=0
        int t = id2 >> 4, s = id2 & 15;
        float vals[16];
        #pragma unroll
        for (int k = 0; k < 16; ++k) vals[k] = 0.f;
        if (t < 173) {
            int xlo = (t > 43) ? (t - 41) / 3 : 0;
            int xhi = t / 3; if (xhi > 43) xhi = 43;
            int x2 = xlo + s;
            if (x2 <= xhi) {
                int y2 = t - 3 * x2;
                int y = y2 + DP, x = x2 + DP, c = y * SZ + x;
                vals[0] = w[c * 25 + 12];
                const int ldy[12] = { 1, 2, -2,-1, 0, 1, 2, -2,-1, 0, 1, 2};
                const int ldx[12] = { 0, 0,  1, 1, 1, 1, 1,  2, 2, 2, 2, 2};
                #pragma unroll
                for (int k = 0; k < 12; ++k) {
                    int dy = ldy[k], dx = ldx[k];
                    if (is_in(y + dy) && is_in(x + dx)) {
                        int nc = c + dy * SZ + dx;
                        vals[1 + k] = w[nc * 25 + (DP - dy) * 5 + (DP - dx)];
                    }
                }
                vals[13] = (float)(ring_id(y2, x2) + 1);
            }
        }
        float* o = FWseq + id2 * 16;
        #pragma unroll
        for (int k = 0; k < 16; ++k) o[k] = vals[k];
        return;
    }
    int id3 = id2 - FTSTEPS * 16;
    if (id3 < NBOR) {
        // border cell: 24 masked weights + 24 ring indices (u16, packed)
        int y, x;
        border_yx(id3, y, x);
        int c = y * SZ + x;
        float vals[24];
        unsigned short rids[24];
        int k = 0;
        #pragma unroll
        for (int dy = -2; dy <= 2; ++dy) {
            #pragma unroll
            for (int dx = -2; dx <= 2; ++dx) {
                if (dy == 0 && dx == 0) continue;
                float v = 0.f; unsigned short r = 0;
                if (is_in(y + dy) && is_in(x + dx)) {
                    int nc = c + dy * SZ + dx;
                    v = w[nc * 25 + (DP - dy) * 5 + (DP - dx)];
                    r = (unsigned short)ring_id(y + dy - DP, x + dx - DP);
                }
                vals[k] = v; rids[k] = r; ++k;
            }
        }
        float* o = FBn + id3 * FB_STRIDE;
        #pragma unroll
        for (int k2 = 0; k2 < 24; ++k2) o[k2] = vals[k2];
        unsigned* oi = (unsigned*)(o + 24);
        #pragma unroll
        for (int k2 = 0; k2 < 12; ++k2)
            oi[k2] = (unsigned)rids[2 * k2] | ((unsigned)rids[2 * k2 + 1] << 16);
    }
}

// ---------------- device helpers ----------------
__device__ __forceinline__ void do_step(int tt, int s, float* gb,
                                        float4 w0, float4 w1, float4 w2)
{
    int xlo = (tt > 43) ? (tt - 41) / 3 : 0;
    int xhi = tt / 3; if (xhi > 43) xhi = 43;
    int x2 = xlo + s;
    if (x2 <= xhi) {
        int cell = (tt - 3 * x2 + DP) * SZ + x2 + DP;
        const float* p = gb + cell - 98;
        float a0 = w0.x * p[0]   + w0.y * p[48]  + w0.z * p[96] + w0.w * p[144];
        float a1 = w1.x * p[192] + w1.y * p[1]   + w1.z * p[49] + w1.w * p[97];
        float a2 = w2.x * p[145] + w2.y * p[193] + w2.z * p[2]  + w2.w * p[50];
        gb[cell] = p[98] + a0 + a1 + a2;
    }
}

__device__ __forceinline__ void loadw3(const float* wfbase, int tt,
                                       float4& w0, float4& w1, float4& w2)
{
    int ci = tt < TSTEPS - 1 ? tt : TSTEPS - 1;
    const float4* q = (const float4*)(wfbase + ci * 192);
    w0 = q[0]; w1 = q[1]; w2 = q[2];
}

// finalize one cell IN PLACE: gb[cell] <- out(cell); stash ring V as f16
__device__ __forceinline__ void fin_step(int tt, int s, int bl, float* gb, __half* side,
                                         float4 f0, float4 f1, float4 f2, float4 f3)
{
    if ((unsigned)tt > 172u) return;
    int xlo = (tt > 43) ? (tt - 41) / 3 : 0;
    int xhi = tt / 3; if (xhi > 43) xhi = 43;
    int x2 = xlo + s;
    if (x2 <= xhi) {
        int cell = (tt - 3 * x2 + DP) * SZ + x2 + DP;
        const float* p = gb + cell - 95;
        float v = p[95];
        float o = f0.x * v      + f0.y * p[143] + f0.z * p[191] + f0.w * p[0]
                + f1.x * p[48]  + f1.y * p[96]  + f1.z * p[144] + f1.w * p[192]
                + f2.x * p[1]   + f2.y * p[49]  + f2.z * p[97]  + f2.w * p[145]
                + f3.x * p[193];
        int rid = (int)f3.y;
        if (rid > 0) side[(rid - 1) * NBATCH + bl] = __float2half(v);
        gb[cell] = o;
    }
}

__device__ __forceinline__ void loadw4(const float* fwbase, int tt,
                                       float4& f0, float4& f1, float4& f2, float4& f3)
{
    int ci = tt < 0 ? 0 : (tt < FTSTEPS - 1 ? tt : FTSTEPS - 1);
    const float4* q = (const float4*)(fwbase + ci * 256);
    f0 = q[0]; f1 = q[1]; f2 = q[2]; f3 = q[3];
}

__device__ __forceinline__ void publish_barrier() {
    asm volatile("s_waitcnt lgkmcnt(0)" ::: "memory");
    __builtin_amdgcn_s_barrier();
    asm volatile("" ::: "memory");
}
__device__ __forceinline__ void consume_barrier() {
    asm volatile("" ::: "memory");
    __builtin_amdgcn_s_barrier();
    asm volatile("" ::: "memory");
}

// ---------------- main kernel ----------------
__global__ __launch_bounds__(NT)
void ca_kernel(const float* __restrict__ in, const float* __restrict__ ws,
               float* __restrict__ out)
{
    __shared__ float g[NBATCH * GS];          // 36,928 B (V, then out, in place)
    __shared__ __half side[NRING * NBATCH];   // 2,688 B (ring V for border pass)
    const int tid = threadIdx.x;
    const int b0  = blockIdx.x * NBATCH;

    // load 4 grids (coalesced float4)
    #pragma unroll
    for (int b = 0; b < NBATCH; ++b) {
        const float4* src = (const float4*)(in + (size_t)(b0 + b) * NC);
        float4* dst = (float4*)(g + b * GS);
        for (int i = tid; i < NC / 4; i += NT) dst[i] = src[i];
    }
    __syncthreads();

    const int wid  = tid >> 6;
    const int lane = tid & 63;
    const int bl   = lane & (NBATCH - 1);
    const int s    = lane >> 2;
    float* gb = g + bl * GS;

    if (wid == 0) {
        // -------- producer: forward wavefront recurrence --------
        const float* wfbase = ws + s * 12;           // step stride 192 floats
        float4 A0, A1, A2, B0, B1, B2, C0, C1, C2, D0, D1, D2;
        loadw3(wfbase, 0, A0, A1, A2);
        loadw3(wfbase, 1, B0, B1, B2);
        loadw3(wfbase, 2, C0, C1, C2);
        loadw3(wfbase, 3, D0, D1, D2);
        for (int p = 0; p < NPHASE; ++p) {
            int t = p * 4;
            do_step(t + 0, s, gb, A0, A1, A2);  loadw3(wfbase, t + 4, A0, A1, A2);
            do_step(t + 1, s, gb, B0, B1, B2);  loadw3(wfbase, t + 5, B0, B1, B2);
            do_step(t + 2, s, gb, C0, C1, C2);  loadw3(wfbase, t + 6, C0, C1, C2);
            do_step(t + 3, s, gb, D0, D1, D2);  loadw3(wfbase, t + 7, D0, D1, D2);
            publish_barrier();
        }
    } else {
        // -------- consumer: trailing in-place finalize (lag 12) --------
        // wave0 phase p writes wf 4p..4p+3 and reads wf >= 4p-8;
        // wave1 phase p overwrites wf <= 4p-9 and reads V of wf <= 4p-1. Disjoint.
        const float* fwbase = ws + WF_FLOATS + s * 16;   // step stride 256 floats
        float4 A0, A1, A2, A3, B0, B1, B2, B3, C0, C1, C2, C3, D0, D1, D2, D3;
        loadw4(fwbase, -12, A0, A1, A2, A3);
        loadw4(fwbase, -11, B0, B1, B2, B3);
        loadw4(fwbase, -10, C0, C1, C2, C3);
        loadw4(fwbase,  -9, D0, D1, D2, D3);
        for (int p = 0; p < NPHASE; ++p) {
            int tau = p * 4 - 12;
            fin_step(tau + 0, s, bl, gb, side, A0, A1, A2, A3);  loadw4(fwbase, tau + 4, A0, A1, A2, A3);
            fin_step(tau + 1, s, bl, gb, side, B0, B1, B2, B3);  loadw4(fwbase, tau + 5, B0, B1, B2, B3);
            fin_step(tau + 2, s, bl, gb, side, C0, C1, C2, C3);  loadw4(fwbase, tau + 6, C0, C1, C2, C3);
            fin_step(tau + 3, s, bl, gb, side, D0, D1, D2, D3);  loadw4(fwbase, tau + 7, D0, D1, D2, D3);
            consume_barrier();
        }
    }
    __syncthreads();

    // -------- border finalize: out(p) = in(p) + sum w_k * ringV_k --------
    {
        const float* FBn = ws + WF_FLOATS + FW_FLOATS;
        for (int it = 0; it < 3; ++it) {
            int idx = it * NT + tid;
            if (idx < NBOR) {
                const float* fb = FBn + idx * FB_STRIDE;
                const float4* fw4 = (const float4*)fb;
                float4 w0 = fw4[0], w1 = fw4[1], w2 = fw4[2], w3 = fw4[3], w4 = fw4[4], w5 = fw4[5];
                const uint4* iw = (const uint4*)(fb + 24);
                uint4 i0 = iw[0], i1 = iw[1], i2 = iw[2];
                unsigned pw[12] = {i0.x, i0.y, i0.z, i0.w, i1.x, i1.y, i1.z, i1.w,
                                   i2.x, i2.y, i2.z, i2.w};
                float wt[24] = {w0.x, w0.y, w0.z, w0.w, w1.x, w1.y, w1.z, w1.w,
                                w2.x, w2.y, w2.z, w2.w, w3.x, w3.y, w3.z, w3.w,
                                w4.x, w4.y, w4.z, w4.w, w5.x, w5.y, w5.z, w5.w};
                int y, x;
                border_yx(idx, y, x);
                int c = y * SZ + x;
                #pragma unroll
                for (int b = 0; b < NBATCH; ++b) {
                    float o = g[b * GS + c];
                    #pragma unroll
                    for (int k = 0; k < 24; ++k) {
                        int rid = (int)((pw[k >> 1] >> ((k & 1) * 16)) & 0xffffu);
                        o += wt[k] * __half2float(side[rid * NBATCH + b]);
                    }
                    g[b * GS + c] = o;
                }
            }
        }
    }
    __syncthreads();

    // -------- coalesced grid -> out copy --------
    #pragma unroll
    for (int b = 0; b < NBATCH; ++b) {
        const float4* src = (const float4*)(g + b * GS);
        float4* dst = (float4*)(out + (size_t)(b0 + b) * NC);
        for (int i = tid; i < NC / 4; i += NT) dst[i] = src[i];
    }
}

extern "C" void kernel_launch(void* const* d_in, const int* in_sizes, int n_in,
                              void* d_out, int out_size, void* d_ws, size_t ws_size,
                              hipStream_t stream)
{
    const float* in = (const float*)d_in[0];
    const float* w  = (const float*)d_in[1];
    float* out = (float*)d_out;
    float* ws  = (float*)d_ws;   // needs 379,648 B

    const int batch   = in_sizes[0] / NC;    // 8192
    const int nblocks = batch / NBATCH;      // 2048

    prep_kernel<<<25, 256, 0, stream>>>(w, ws);   // 6400 threads cover all tables
    ca_kernel<<<nblocks, NT, 0, stream>>>(in, ws, out);
}